// Round 1
// baseline (76.684 us; speedup 1.0000x reference)
//
#include <hip/hip_runtime.h>

#define GAMMA_C 0.2f
#define ALPHA_C 0.6f

// Stage 1: grid-stride over float4/int4 vectors, per-block partial sum to ws.
__global__ __launch_bounds__(256) void focal_partial_kernel(
    const float4* __restrict__ logits4,
    const int4* __restrict__ target4,
    float* __restrict__ partial,
    long long nvec,
    const float* __restrict__ logits_s,   // scalar views for tail
    const int* __restrict__ target_s,
    long long n)
{
    long long i = (long long)blockIdx.x * blockDim.x + threadIdx.x;
    const long long stride = (long long)gridDim.x * blockDim.x;

    float acc = 0.0f;
    for (; i < nvec; i += stride) {
        float4 x4 = logits4[i];
        int4   t4 = target4[i];
        float xs[4] = {x4.x, x4.y, x4.z, x4.w};
        int   ts[4] = {t4.x, t4.y, t4.z, t4.w};
#pragma unroll
        for (int j = 0; j < 4; ++j) {
            float x  = xs[j];
            float p  = 1.0f / (1.0f + __expf(-x));
            float lp  = __logf(p);         // log(p)
            float l1p = __logf(1.0f - p);  // log(1-p)
            // (1-p)^g = exp(g*log(1-p)); p^g = exp(g*log(p))
            float pos = -ALPHA_C          * __expf(GAMMA_C * l1p) * lp;
            float neg = -(1.0f - ALPHA_C) * __expf(GAMMA_C * lp)  * l1p;
            acc += (ts[j] == 1) ? pos : neg;
        }
    }

    // Tail (n % 4 != 0) — handled by thread 0 of block 0 (n is 4-divisible
    // for this problem, so this is a no-op safety net).
    if (blockIdx.x == 0 && threadIdx.x == 0) {
        for (long long k = nvec * 4; k < n; ++k) {
            float x  = logits_s[k];
            int   t  = target_s[k];
            float p  = 1.0f / (1.0f + __expf(-x));
            float lp  = __logf(p);
            float l1p = __logf(1.0f - p);
            float pos = -ALPHA_C          * __expf(GAMMA_C * l1p) * lp;
            float neg = -(1.0f - ALPHA_C) * __expf(GAMMA_C * lp)  * l1p;
            acc += (t == 1) ? pos : neg;
        }
    }

    // Wave (64-lane) reduction
#pragma unroll
    for (int off = 32; off > 0; off >>= 1)
        acc += __shfl_down(acc, off, 64);

    __shared__ float smem[4];
    int lane = threadIdx.x & 63;
    int wid  = threadIdx.x >> 6;
    if (lane == 0) smem[wid] = acc;
    __syncthreads();
    if (threadIdx.x == 0)
        partial[blockIdx.x] = smem[0] + smem[1] + smem[2] + smem[3];
}

// Stage 2: deterministic reduce of per-block partials, apply mean, write out.
__global__ __launch_bounds__(256) void focal_final_kernel(
    const float* __restrict__ partial,
    int nblocks,
    float inv_count,
    float* __restrict__ out)
{
    float acc = 0.0f;
    for (int i = threadIdx.x; i < nblocks; i += 256)
        acc += partial[i];

#pragma unroll
    for (int off = 32; off > 0; off >>= 1)
        acc += __shfl_down(acc, off, 64);

    __shared__ float smem[4];
    int lane = threadIdx.x & 63;
    int wid  = threadIdx.x >> 6;
    if (lane == 0) smem[wid] = acc;
    __syncthreads();
    if (threadIdx.x == 0)
        out[0] = (smem[0] + smem[1] + smem[2] + smem[3]) * inv_count;
}

extern "C" void kernel_launch(void* const* d_in, const int* in_sizes, int n_in,
                              void* d_out, int out_size, void* d_ws, size_t ws_size,
                              hipStream_t stream) {
    const float* logits = (const float*)d_in[0];
    const int*   target = (const int*)d_in[1];
    long long n = (long long)in_sizes[0];     // N*C = 41,943,040
    long long nvec = n / 4;

    float* partial = (float*)d_ws;
    const int nblocks = 2048;                 // 256 CU × 8 blocks
    const int nthreads = 256;

    focal_partial_kernel<<<nblocks, nthreads, 0, stream>>>(
        (const float4*)logits, (const int4*)target, partial, nvec,
        logits, target, n);
    focal_final_kernel<<<1, nthreads, 0, stream>>>(
        partial, nblocks, 1.0f / (float)n, (float*)d_out);
}

// Round 2
// 63.704 us; speedup vs baseline: 1.2037x; 1.2037x over previous
//
#include <hip/hip_runtime.h>

#define GAMMA_C 0.2f

// log2(e) and coefficients with ln2 folded in:
// pos = ALPHA     * ln2 * s2 * exp2(-g*a2)
// neg = (1-ALPHA) * ln2 * a2 * exp2(-g*s2)
// where s2 = log2(1 + exp2(-x*log2e)), a2 = x*log2e + s2.
#define L2E_C 1.4426950408889634f
#define CPOS_C 0.41588830833596715f  // 0.6 * ln2
#define CNEG_C 0.27725887222397810f  // 0.4 * ln2

__device__ __forceinline__ float focal_elem(float x, int t) {
    float xl = x * L2E_C;
    float e  = __builtin_amdgcn_exp2f(-xl);       // exp2(-x*log2e) = exp(-x)
    float s2 = __builtin_amdgcn_logf(1.0f + e);   // log2(1+exp(-x)) = softplus(-x)/ln2
    float a2 = xl + s2;                           // (x + softplus(-x))/ln2
    bool ispos = (t == 1);
    float earg = ispos ? a2 : s2;
    float fac  = ispos ? s2 : a2;
    float cf   = ispos ? CPOS_C : CNEG_C;
    float ex   = __builtin_amdgcn_exp2f(-GAMMA_C * earg);
    return cf * fac * ex;
}

// Stage 1: grid-stride over float4/int4 vectors, per-block partial sum to ws.
__global__ __launch_bounds__(256) void focal_partial_kernel(
    const float4* __restrict__ logits4,
    const int4* __restrict__ target4,
    float* __restrict__ partial,
    long long nvec,
    const float* __restrict__ logits_s,   // scalar views for tail
    const int* __restrict__ target_s,
    long long n)
{
    const long long stride = (long long)gridDim.x * blockDim.x;
    long long i = (long long)blockIdx.x * blockDim.x + threadIdx.x;

    float acc = 0.0f;
    // 2-deep unroll: two independent 16B load pairs in flight per iteration.
    for (; i + stride < nvec; i += 2 * stride) {
        float4 x4a = logits4[i];
        int4   t4a = target4[i];
        float4 x4b = logits4[i + stride];
        int4   t4b = target4[i + stride];
        acc += focal_elem(x4a.x, t4a.x);
        acc += focal_elem(x4a.y, t4a.y);
        acc += focal_elem(x4a.z, t4a.z);
        acc += focal_elem(x4a.w, t4a.w);
        acc += focal_elem(x4b.x, t4b.x);
        acc += focal_elem(x4b.y, t4b.y);
        acc += focal_elem(x4b.z, t4b.z);
        acc += focal_elem(x4b.w, t4b.w);
    }
    if (i < nvec) {
        float4 x4 = logits4[i];
        int4   t4 = target4[i];
        acc += focal_elem(x4.x, t4.x);
        acc += focal_elem(x4.y, t4.y);
        acc += focal_elem(x4.z, t4.z);
        acc += focal_elem(x4.w, t4.w);
    }

    // Tail (n % 4 != 0) — no-op for this problem shape.
    if (blockIdx.x == 0 && threadIdx.x == 0) {
        for (long long k = nvec * 4; k < n; ++k)
            acc += focal_elem(logits_s[k], target_s[k]);
    }

    // Wave (64-lane) reduction
#pragma unroll
    for (int off = 32; off > 0; off >>= 1)
        acc += __shfl_down(acc, off, 64);

    __shared__ float smem[4];
    int lane = threadIdx.x & 63;
    int wid  = threadIdx.x >> 6;
    if (lane == 0) smem[wid] = acc;
    __syncthreads();
    if (threadIdx.x == 0)
        partial[blockIdx.x] = smem[0] + smem[1] + smem[2] + smem[3];
}

// Stage 2: deterministic reduce of per-block partials, apply mean, write out.
__global__ __launch_bounds__(256) void focal_final_kernel(
    const float* __restrict__ partial,
    int nblocks,
    float inv_count,
    float* __restrict__ out)
{
    float acc = 0.0f;
    for (int i = threadIdx.x; i < nblocks; i += 256)
        acc += partial[i];

#pragma unroll
    for (int off = 32; off > 0; off >>= 1)
        acc += __shfl_down(acc, off, 64);

    __shared__ float smem[4];
    int lane = threadIdx.x & 63;
    int wid  = threadIdx.x >> 6;
    if (lane == 0) smem[wid] = acc;
    __syncthreads();
    if (threadIdx.x == 0)
        out[0] = (smem[0] + smem[1] + smem[2] + smem[3]) * inv_count;
}

extern "C" void kernel_launch(void* const* d_in, const int* in_sizes, int n_in,
                              void* d_out, int out_size, void* d_ws, size_t ws_size,
                              hipStream_t stream) {
    const float* logits = (const float*)d_in[0];
    const int*   target = (const int*)d_in[1];
    long long n = (long long)in_sizes[0];     // N*C = 41,943,040
    long long nvec = n / 4;

    float* partial = (float*)d_ws;
    const int nblocks = 2048;                 // 256 CU x 8 blocks
    const int nthreads = 256;

    focal_partial_kernel<<<nblocks, nthreads, 0, stream>>>(
        (const float4*)logits, (const int4*)target, partial, nvec,
        logits, target, n);
    focal_final_kernel<<<1, nthreads, 0, stream>>>(
        partial, nblocks, 1.0f / (float)n, (float*)d_out);
}

// Round 3
// 63.422 us; speedup vs baseline: 1.2091x; 1.0044x over previous
//
#include <hip/hip_runtime.h>

#define GAMMA_C 0.2f

// pos = ALPHA     * ln2 * s2 * exp2(-g*a2)
// neg = (1-ALPHA) * ln2 * a2 * exp2(-g*s2)
// where s2 = log2(1 + exp2(-x*log2e)), a2 = x*log2e + s2.
#define L2E_C 1.4426950408889634f
#define CPOS_C 0.41588830833596715f  // 0.6 * ln2
#define CNEG_C 0.27725887222397810f  // 0.4 * ln2

__device__ __forceinline__ float focal_elem(float x, int t) {
    float xl = x * L2E_C;
    float e  = __builtin_amdgcn_exp2f(-xl);       // exp(-x)
    float s2 = __builtin_amdgcn_logf(1.0f + e);   // softplus(-x)/ln2
    float a2 = xl + s2;                           // (x + softplus(-x))/ln2
    bool ispos = (t == 1);
    float earg = ispos ? a2 : s2;
    float fac  = ispos ? s2 : a2;
    float cf   = ispos ? CPOS_C : CNEG_C;
    float ex   = __builtin_amdgcn_exp2f(-GAMMA_C * earg);
    return cf * fac * ex;
}

__device__ __forceinline__ float focal_vec4(float4 x4, int4 t4) {
    float r = focal_elem(x4.x, t4.x);
    r += focal_elem(x4.y, t4.y);
    r += focal_elem(x4.z, t4.z);
    r += focal_elem(x4.w, t4.w);
    return r;
}

// Stage 1: grid-stride over float4/int4 vectors, per-block partial sum to ws.
__global__ __launch_bounds__(256) void focal_partial_kernel(
    const float4* __restrict__ logits4,
    const int4* __restrict__ target4,
    float* __restrict__ partial,
    long long nvec,
    const float* __restrict__ logits_s,   // scalar views for tail
    const int* __restrict__ target_s,
    long long n)
{
    const long long stride = (long long)gridDim.x * blockDim.x;
    long long i = (long long)blockIdx.x * blockDim.x + threadIdx.x;

    float a0 = 0.0f, a1 = 0.0f, a2 = 0.0f, a3 = 0.0f;

    // 4-deep unroll: 8 independent 16B loads in flight per iteration,
    // 4 independent accumulator chains.
    for (; i + 3 * stride < nvec; i += 4 * stride) {
        float4 x0 = logits4[i];
        float4 x1 = logits4[i + stride];
        float4 x2 = logits4[i + 2 * stride];
        float4 x3 = logits4[i + 3 * stride];
        int4   t0 = target4[i];
        int4   t1 = target4[i + stride];
        int4   t2 = target4[i + 2 * stride];
        int4   t3 = target4[i + 3 * stride];
        a0 += focal_vec4(x0, t0);
        a1 += focal_vec4(x1, t1);
        a2 += focal_vec4(x2, t2);
        a3 += focal_vec4(x3, t3);
    }
    for (; i < nvec; i += stride)
        a0 += focal_vec4(logits4[i], target4[i]);

    float acc = (a0 + a1) + (a2 + a3);

    // Tail (n % 4 != 0) — no-op for this problem shape.
    if (blockIdx.x == 0 && threadIdx.x == 0) {
        for (long long k = nvec * 4; k < n; ++k)
            acc += focal_elem(logits_s[k], target_s[k]);
    }

    // Wave (64-lane) reduction
#pragma unroll
    for (int off = 32; off > 0; off >>= 1)
        acc += __shfl_down(acc, off, 64);

    __shared__ float smem[4];
    int lane = threadIdx.x & 63;
    int wid  = threadIdx.x >> 6;
    if (lane == 0) smem[wid] = acc;
    __syncthreads();
    if (threadIdx.x == 0)
        partial[blockIdx.x] = smem[0] + smem[1] + smem[2] + smem[3];
}

// Stage 2: deterministic reduce of per-block partials, apply mean, write out.
__global__ __launch_bounds__(256) void focal_final_kernel(
    const float* __restrict__ partial,
    int nblocks,
    float inv_count,
    float* __restrict__ out)
{
    float acc = 0.0f;
    for (int i = threadIdx.x; i < nblocks; i += 256)
        acc += partial[i];

#pragma unroll
    for (int off = 32; off > 0; off >>= 1)
        acc += __shfl_down(acc, off, 64);

    __shared__ float smem[4];
    int lane = threadIdx.x & 63;
    int wid  = threadIdx.x >> 6;
    if (lane == 0) smem[wid] = acc;
    __syncthreads();
    if (threadIdx.x == 0)
        out[0] = (smem[0] + smem[1] + smem[2] + smem[3]) * inv_count;
}

extern "C" void kernel_launch(void* const* d_in, const int* in_sizes, int n_in,
                              void* d_out, int out_size, void* d_ws, size_t ws_size,
                              hipStream_t stream) {
    const float* logits = (const float*)d_in[0];
    const int*   target = (const int*)d_in[1];
    long long n = (long long)in_sizes[0];     // N*C = 41,943,040
    long long nvec = n / 4;

    float* partial = (float*)d_ws;
    const int nblocks = 2048;                 // 256 CU x 8 blocks
    const int nthreads = 256;

    focal_partial_kernel<<<nblocks, nthreads, 0, stream>>>(
        (const float4*)logits, (const int4*)target, partial, nvec,
        logits, target, n);
    focal_final_kernel<<<1, nthreads, 0, stream>>>(
        partial, nblocks, 1.0f / (float)n, (float*)d_out);
}